// Round 7
// baseline (335.539 us; speedup 1.0000x reference)
//
#include <hip/hip_runtime.h>
#include <hip/hip_bf16.h>
#include <hip/hip_fp16.h>
#include <cmath>

// Problem constants
#define Bv   2
#define Tv   8
#define Hv   64
#define Wv   64
#define MPOS (Bv*Tv*Hv*Wv)           // 65536 positions
#define SCALEv 0.17677669529663687f  // 32^-0.5

// Attention tiling: 8x8 queries (one t, one b, one head) per block.
// 3 passes, one per time-slice ut. 196 spatial union positions per pass.
// R7: ALL intermediate buffers are HEAD-MAJOR [head][pos][32] so lines are
// single-block-owned (kills cross-XCD partial-line RMW + read amplification).
#define SPOS  196                    // 14x14 spatial union per time slice
#define SVT   464                    // Vt/P row stride bytes (116 dw == 20 mod 32)
#define NCOLS 232                    // row stride in ushorts

// LDS layout (bytes)
#define KOFF   0                     // K: 208 slots x 64 B (13 x 1KB chunks)
#define VTOFF  13312                 // Vt: 32 x 464 B, XOR-swizzled (d>>3)<<5
#define POFF   28160                 // P : 64 x 464 B (f16 raw -> bf16 exp)
#define RPBOFF 57856                 // 845 f32 (this head's rpb)
#define INVOFF 61248                 // 64 f32 (1/sum)
#define SCROFF 61504                 // 16 waves x 64 lanes x 16 B AV partials
#define SMEM_BYTES 77888             // <= 81920 -> 2 blocks/CU (8 waves/SIMD)

// GEMM LDS row padding: 136 bf16 = 272 B; 272/4 = 68 dwords == 4 (mod 32)
#define KPAD 136

typedef __attribute__((ext_vector_type(8))) short bf16x8;   // MFMA A/B frag
typedef __attribute__((ext_vector_type(4))) float f32x4;    // MFMA C/D frag

__device__ __forceinline__ unsigned short f2bf16(float x) {
  return __builtin_bit_cast(unsigned short, __float2bfloat16(x));
}
__device__ __forceinline__ float bf2f(unsigned short h) {
  return __uint_as_float((unsigned)h << 16);
}
__device__ __forceinline__ float h2f(unsigned short h) {
  return __half2float(__builtin_bit_cast(__half, h));
}
__device__ __forceinline__ unsigned short f2h(float x) {
  return __builtin_bit_cast(unsigned short, __float2half(x));
}
__device__ __forceinline__ unsigned pk2(float a, float b) {
  return (unsigned)f2bf16(a) | ((unsigned)f2bf16(b) << 16);
}
// async global->LDS, 16B per lane; dest = wave-uniform base + lane*16
__device__ __forceinline__ void gload_lds16(const void* gsrc, void* ldst) {
  __builtin_amdgcn_global_load_lds(
      (const __attribute__((address_space(1))) unsigned int*)gsrc,
      (__attribute__((address_space(3))) unsigned int*)ldst, 16, 0, 0);
}

// ---------------------------------------------------------------------------
// Preconvert weights: transpose to [n][k] bf16 with KPAD row stride.
// ---------------------------------------------------------------------------
__global__ __launch_bounds__(256) void preconvert(
    const float* __restrict__ qv_w, const float* __restrict__ k_w,
    const float* __restrict__ proj_w,
    ushort* __restrict__ wqvT, ushort* __restrict__ wkT,
    ushort* __restrict__ wpT_hi, ushort* __restrict__ wpT_lo) {
  const int id = blockIdx.x * 256 + threadIdx.x;
  if (id < 32768) {                       // qv: n<256, k<128
    const int n = id >> 7, kk = id & 127;
    wqvT[n * KPAD + kk] = f2bf16(qv_w[kk * 256 + n]);
  } else if (id < 49152) {                // k: n<128
    const int j = id - 32768;
    const int n = j >> 7, kk = j & 127;
    wkT[n * KPAD + kk] = f2bf16(k_w[kk * 128 + n]);
  } else {                                // proj: hi/lo split
    const int j = id - 49152;
    const int n = j >> 7, kk = j & 127;
    const float v = proj_w[kk * 128 + n];
    const unsigned short hi = f2bf16(v);
    wpT_hi[n * KPAD + kk] = hi;
    wpT_lo[n * KPAD + kk] = f2bf16(v - bf2f(hi));
  }
}

// ---------------------------------------------------------------------------
// Fused q/v (256-col, x read once) + k (128-col) projection GEMMs.
// Grid 1024: bx<512 -> qv from x; bx>=512 -> k from y.
// Outputs HEAD-MAJOR: buf[head][pos][32] bf16.
// ---------------------------------------------------------------------------
__global__ __launch_bounds__(512) void gemm_qvk(
    const float* __restrict__ x, const float* __restrict__ y,
    const ushort* __restrict__ wqvT, const ushort* __restrict__ wkT,
    const float* __restrict__ qv_b, const float* __restrict__ k_b,
    ushort* __restrict__ qbuf, ushort* __restrict__ vbuf,
    ushort* __restrict__ kbuf) {
  __shared__ ushort Ws[256 * KPAD];
  const int tid  = threadIdx.x;
  const int bx   = blockIdx.x;
  const bool isK = (bx >= 512);
  const int row0 = (bx & 511) * 128;

  const float* A = isK ? y : x;
  {
    const uint4* wg = (const uint4*)(isK ? wkT : wqvT);
    const int nW = isK ? 2176 : 4352;
    for (int i = tid; i < nW; i += 512)
      gload_lds16(wg + i, (uint4*)Ws + i);
  }

  const int wv = tid >> 6, lane = tid & 63, quad = lane >> 4, l16 = lane & 15;
  const int arow = row0 + wv * 16 + l16;

  bf16x8 af[4];
#pragma unroll
  for (int kk = 0; kk < 4; ++kk) {
    const float4* ap = (const float4*)(A + (size_t)arow * 128 + kk * 32 + quad * 8);
    const float4 a = ap[0], b2 = ap[1];
    af[kk] = __builtin_bit_cast(bf16x8,
        make_uint4(pk2(a.x, a.y), pk2(a.z, a.w), pk2(b2.x, b2.y), pk2(b2.z, b2.w)));
  }
  __syncthreads();

  const int NT = isK ? 8 : 16;
  f32x4 C[16];
#pragma unroll
  for (int nt = 0; nt < 16; ++nt) C[nt] = (f32x4){0.f, 0.f, 0.f, 0.f};

  for (int nt = 0; nt < NT; ++nt) {
#pragma unroll
    for (int kk = 0; kk < 4; ++kk) {
      const bf16x8 b2 = *(const bf16x8*)(Ws + (nt * 16 + l16) * KPAD + kk * 32 + quad * 8);
      C[nt] = __builtin_amdgcn_mfma_f32_16x16x32_bf16(af[kk], b2, C[nt], 0, 0, 0);
    }
  }

  for (int nt = 0; nt < NT; ++nt) {
    const int col = nt * 16 + l16;
    const float bv = isK ? k_b[col] : qv_b[col];
#pragma unroll
    for (int r2 = 0; r2 < 4; ++r2) {
      const size_t row = row0 + wv * 16 + quad * 4 + r2;
      const float val = C[nt][r2] + bv;
      if (isK) {
        kbuf[(size_t)(col >> 5) * MPOS * 32 + row * 32 + (col & 31)] = f2bf16(val);
      } else if (col < 128) {
        qbuf[(size_t)(col >> 5) * MPOS * 32 + row * 32 + (col & 31)] =
            f2bf16(val * SCALEv);
      } else {
        const int vc2 = col - 128;
        vbuf[(size_t)(vc2 >> 5) * MPOS * 32 + row * 32 + (vc2 & 31)] = f2bf16(val);
      }
    }
  }
}

// ---------------------------------------------------------------------------
// Output projection, bf16x3 (fp32-accurate). obuf is HEAD-MAJOR; the kk-th
// 32-wide K-block of the proj GEMM == head kk exactly.
// ---------------------------------------------------------------------------
__global__ __launch_bounds__(512) void gemm_proj_mfma(
    const float* __restrict__ o, const ushort* __restrict__ wpT_hi,
    const ushort* __restrict__ wpT_lo, const float* __restrict__ proj_b,
    float* __restrict__ out) {
  __shared__ ushort Wh[128 * KPAD];
  __shared__ ushort Wl[128 * KPAD];
  const int tid  = threadIdx.x;
  const int row0 = blockIdx.x * 128;
  {
    const uint4* wgh = (const uint4*)wpT_hi;
    const uint4* wgl = (const uint4*)wpT_lo;
    for (int i = tid; i < 2176; i += 512) {
      gload_lds16(wgh + i, (uint4*)Wh + i);
      gload_lds16(wgl + i, (uint4*)Wl + i);
    }
  }

  const int wv = tid >> 6, lane = tid & 63, quad = lane >> 4, l16 = lane & 15;
  const int arow = row0 + wv * 16 + l16;

  bf16x8 ah[4], al[4];
#pragma unroll
  for (int kk = 0; kk < 4; ++kk) {
    const float4* ap =
        (const float4*)(o + (size_t)kk * MPOS * 32 + (size_t)arow * 32 + quad * 8);
    const float4 a = ap[0], b2 = ap[1];
    const float vs[8] = {a.x, a.y, a.z, a.w, b2.x, b2.y, b2.z, b2.w};
    unsigned hw[4], lw[4];
#pragma unroll
    for (int e = 0; e < 4; ++e) {
      const unsigned short h0 = f2bf16(vs[2 * e]);
      const unsigned short h1 = f2bf16(vs[2 * e + 1]);
      hw[e] = (unsigned)h0 | ((unsigned)h1 << 16);
      lw[e] = (unsigned)f2bf16(vs[2 * e] - bf2f(h0)) |
              ((unsigned)f2bf16(vs[2 * e + 1] - bf2f(h1)) << 16);
    }
    ah[kk] = __builtin_bit_cast(bf16x8, make_uint4(hw[0], hw[1], hw[2], hw[3]));
    al[kk] = __builtin_bit_cast(bf16x8, make_uint4(lw[0], lw[1], lw[2], lw[3]));
  }
  __syncthreads();

  f32x4 C[8];
#pragma unroll
  for (int nt = 0; nt < 8; ++nt) C[nt] = (f32x4){0.f, 0.f, 0.f, 0.f};

#pragma unroll
  for (int kk = 0; kk < 4; ++kk) {
#pragma unroll
    for (int nt = 0; nt < 8; ++nt) {
      const int boff = (nt * 16 + l16) * KPAD + kk * 32 + quad * 8;
      const bf16x8 bh = *(const bf16x8*)(Wh + boff);
      const bf16x8 bl = *(const bf16x8*)(Wl + boff);
      C[nt] = __builtin_amdgcn_mfma_f32_16x16x32_bf16(ah[kk], bh, C[nt], 0, 0, 0);
      C[nt] = __builtin_amdgcn_mfma_f32_16x16x32_bf16(ah[kk], bl, C[nt], 0, 0, 0);
      C[nt] = __builtin_amdgcn_mfma_f32_16x16x32_bf16(al[kk], bh, C[nt], 0, 0, 0);
    }
  }

#pragma unroll
  for (int nt = 0; nt < 8; ++nt) {
    const int col = nt * 16 + l16;
    const float bv = proj_b[col];
#pragma unroll
    for (int r2 = 0; r2 < 4; ++r2) {
      const size_t row = row0 + wv * 16 + quad * 4 + r2;
      out[row * 128 + col] = C[nt][r2] + bv;
    }
  }
}

// ---------------------------------------------------------------------------
// MFMA NA3D attention. Block = 8x8 query tile (one b,t,head), 1024 thr.
// 3 passes (one per ut), K via global_load_lds, 77.9 KB LDS -> 2 blocks/CU.
// R7: head-major I/O — per-position 64 B chunks, wave-contiguous 512 B stores.
// ---------------------------------------------------------------------------
__global__ __launch_bounds__(1024, 8)
void na3d_tile(
    const ushort* __restrict__ qin,
    const ushort* __restrict__ kin,
    const ushort* __restrict__ vin,
    const float* __restrict__ rpb,
    float* __restrict__ oout) {
  __shared__ __align__(16) unsigned char smem[SMEM_BYTES];

  const int tid  = threadIdx.x;
  const int wv   = tid >> 6;          // 0..15
  const int lane = tid & 63;
  const int quad = lane >> 4;
  const int l16  = lane & 15;

  const int bx   = blockIdx.x;
  const int head = bx & 3;
  const int tile = bx >> 2;
  const int w0 = (tile & 7) << 3;
  const int h0 = ((tile >> 3) & 7) << 3;
  const int t  = (tile >> 6) & 7;
  const int b  = tile >> 9;

  const int st  = min(max(t - 1, 0), Tv - 3);
  const int u_h = min(max(h0 - 3, 0), Hv - 14);
  const int u_w = min(max(w0 - 3, 0), Wv - 14);
  const int rt_b = st - t + 2;   // 0..2

  // head-major bases
  const ushort* qin_h = qin + (size_t)head * MPOS * 32;
  const uint4*  kin_h = (const uint4*)kin + (size_t)head * MPOS * 4;
  const uint4*  vin_h = (const uint4*)vin + (size_t)head * MPOS * 4;
  float*        oout_h = oout + (size_t)head * MPOS * 32;

  // Q A-frag (pass-invariant)
  const int mtile = wv & 3;
  bf16x8 afrag;
  {
    const int q_a  = mtile * 16 + l16;
    const int qh_a = h0 + (q_a >> 3), qw_a = w0 + (q_a & 7);
    const size_t qpos_a = ((size_t)(b * Tv + t) * Hv + qh_a) * Wv + qw_a;
    afrag = *(const bf16x8*)(qin_h + qpos_a * 32 + quad * 8);
  }
  // rpb -> LDS
  if (tid < 845) ((float*)(smem + RPBOFF))[tid] = rpb[head * 845 + tid];

  // softmax geometry (pass-invariant)
  const int qs = tid >> 4, l16s = tid & 15;
  const int qh_s = h0 + (qs >> 3), qw_s = w0 + (qs & 7);
  const int sh_s = min(max(qh_s - 3, 0), Hv - 7);
  const int sw_s = min(max(qw_s - 3, 0), Wv - 7);
  const int dh_s = sh_s - u_h, dw_s = sw_s - u_w;          // [0,7]
  const int rh0 = sh_s - qh_s + 6, rw0 = sw_s - qw_s + 6;  // [0,6]

  // AV wave mapping (pass-invariant)
  const int khalf = wv >> 3, mtA = (wv >> 1) & 3, ntA = wv & 1;
  const int dcol = ntA * 16 + l16;
  const unsigned vsw = ((unsigned)(dcol >> 3) & 3u) << 5;

  // V/K staging decode (pass-invariant; per-position 4 uint4 chunks)
  const int vpos = tid >> 2, vc = tid & 3;       // V: tid<784
  const int vrh = vpos / 14, vrw = vpos - vrh * 14;
  const size_t vsp = ((size_t)(u_h + vrh) * Wv + (u_w + vrw)) * 4 + vc;
  // K: wave wv<13 stages chunk wv
  const int km = wv * 64 + lane;
  const int kpos0 = min(km >> 2, SPOS - 1);
  const int kslot = km & 3;
  const int kc = (kslot - (kpos0 >> 2)) & 3;
  const int krh = kpos0 / 14, krw = kpos0 - krh * 14;
  const size_t ksp = ((size_t)(u_h + krh) * Wv + (u_w + krw)) * 4 + kc;

  f32x4 o = {0.f, 0.f, 0.f, 0.f};
  float sum = 0.f;
  uint4 vv;

  // prologue: issue V + K for pass 0
  {
    const size_t tbase = (size_t)(b * Tv + st) * Hv * Wv * 4;
    if (tid < SPOS * 4) vv = vin_h[tbase + vsp];
    if (wv < 13)
      gload_lds16(kin_h + tbase + ksp, smem + KOFF + wv * 1024 + lane * 16);
  }

#pragma unroll 1
  for (int pass = 0; pass < 3; ++pass) {
    // ---- V repack -> Vt (XOR-swizzled) ----
    if (tid < SPOS * 4) {
      const unsigned sw = (unsigned)vc << 5;     // d>>3 == vc for this chunk
      const unsigned v4[4] = {vv.x, vv.y, vv.z, vv.w};
#pragma unroll
      for (int m2 = 0; m2 < 4; ++m2) {
        const int d0 = 8 * vc + 2 * m2;
        const unsigned base = (unsigned)d0 * SVT + (unsigned)vpos * 2;
        *(ushort*)(smem + VTOFF + (base ^ sw))         = (ushort)(v4[m2] & 0xffffu);
        *(ushort*)(smem + VTOFF + ((base + SVT) ^ sw)) = (ushort)(v4[m2] >> 16);
      }
    }
    // Vt tail zero: cols 196..231 (18 dwords x 32 rows), pass 0 only
    if (pass == 0 && tid < 576) {
      const int d = tid / 18, jj = tid - d * 18;
      const unsigned base = (unsigned)d * SVT + 392u + (unsigned)jj * 4;
      *(unsigned*)(smem + VTOFF + (base ^ (((unsigned)d >> 3) << 5))) = 0u;
    }
    __syncthreads();   // (A) K + Vt ready (vmcnt drained by barrier)

    // ---- QK: 13 tiles over 4 wave-groups, raw f16 scores -> P ----
    {
      ushort* ph = (ushort*)(smem + POFF);
      for (int nt = (wv >> 2); nt < 13; nt += 4) {
        const int u = nt * 16 + l16;
        const int slot = (quad + (u >> 2)) & 3;
        const bf16x8 bfrag = *(const bf16x8*)(smem + KOFF + u * 64 + slot * 16);
        f32x4 c = {0.f, 0.f, 0.f, 0.f};
        c = __builtin_amdgcn_mfma_f32_16x16x32_bf16(afrag, bfrag, c, 0, 0, 0);
#pragma unroll
        for (int r2 = 0; r2 < 4; ++r2) {
          const int qrow = mtile * 16 + quad * 4 + r2;
          ph[qrow * NCOLS + u] = f2h(c[r2]);
        }
      }
    }
    __syncthreads();   // (B) P raw ready

    // ---- softmax: 49 valid / query (7 runs of 7), read+exp -> zero -> scatter
    {
      const ushort* Ps = (const ushort*)(smem + POFF) + qs * NCOLS;
      const float* rpb_l = (const float*)(smem + RPBOFF) + (rt_b + pass) * 169;
      float ex[4];
      int uu[4];
#pragma unroll
      for (int k = 0; k < 4; ++k) {
        const int e = l16s + 16 * k;
        const int a = (e * 37) >> 8;             // e/7 for e<64
        const int bb = e - 7 * a;
        uu[k] = (dh_s + a) * 14 + dw_s + bb;
        if (e < 49) {
          const float s = h2f(Ps[uu[k]]) + rpb_l[(rh0 + a) * 13 + rw0 + bb];
          ex[k] = __expf(s);
          sum += ex[k];
        }
      }
      if (pass == 2) {
        float sm = sum;
        sm += __shfl_xor(sm, 1);
        sm += __shfl_xor(sm, 2);
        sm += __shfl_xor(sm, 4);
        sm += __shfl_xor(sm, 8);
        if (l16s == 0) ((float*)(smem + INVOFF))[qs] = 1.0f / sm;
      }
      __builtin_amdgcn_sched_barrier(0);         // reads before zeros
      {
        uint4* Pv = (uint4*)(smem + POFF + (size_t)qs * SVT);
        Pv[l16s] = make_uint4(0u, 0u, 0u, 0u);
        if (l16s < 13) Pv[l16s + 16] = make_uint4(0u, 0u, 0u, 0u);
      }
      __builtin_amdgcn_sched_barrier(0);         // zeros before scatter
      ushort* Pr = (ushort*)(smem + POFF) + qs * NCOLS;
#pragma unroll
      for (int k = 0; k < 4; ++k) {
        const int e = l16s + 16 * k;
        if (e < 49) Pr[uu[k]] = f2bf16(ex[k]);
      }
    }
    __syncthreads();   // (E) P ready

    // ---- issue next pass's V + K (drains at barrier F, hidden by AV) ----
    if (pass < 2) {
      const size_t tbase = (size_t)(b * Tv + st + pass + 1) * Hv * Wv * 4;
      if (tid < SPOS * 4) vv = vin_h[tbase + vsp];
      if (wv < 13)
        gload_lds16(kin_h + tbase + ksp, smem + KOFF + wv * 1024 + lane * 16);
    }

    // ---- AV: 7 kts split across wave halves, accumulate across passes ----
    {
      const unsigned char* Abase = smem + POFF + (size_t)(mtA * 16 + l16) * SVT;
      const unsigned vlocal = (unsigned)dcol * SVT;
      const int kt0 = khalf ? 4 : 0;
      const int kt1 = khalf ? 7 : 4;
      for (int kt = kt0; kt < kt1; ++kt) {
        const bf16x8 a  = *(const bf16x8*)(Abase + kt * 64 + quad * 16);
        const bf16x8 bb = *(const bf16x8*)(smem + VTOFF +
                            ((vlocal + kt * 64 + quad * 16) ^ vsw));
        o = __builtin_amdgcn_mfma_f32_16x16x32_bf16(a, bb, o, 0, 0, 0);
      }
    }
    if (pass < 2) __syncthreads();   // (F) AV reads done -> restage Vt/K/P
  }

  // ---- epilogue: all partials -> LDS, combine, contiguous 512 B/wave ----
  {
    f32x4* part = (f32x4*)(smem + SCROFF);
    part[wv * 64 + lane] = o;
    __syncthreads();
    const float* pf = (const float*)(smem + SCROFF);
    const float* invArr = (const float*)(smem + INVOFF);
    const int colw = lane & 31;              // 0..31
    const int nt2 = colw >> 4, l16w = colw & 15;
#pragma unroll
    for (int i = 0; i < 2; ++i) {
      const int q = 4 * wv + 2 * i + (lane >> 5);   // 0..63
      const int mt = q >> 4, qd = (q >> 2) & 3, r2 = q & 3;
      const int idx0 = (((mt * 2 + nt2) * 64) + qd * 16 + l16w) * 4 + r2;
      const float val = (pf[idx0] + pf[idx0 + 2048]) * invArr[q]; // +8 waves
      const int qh2 = h0 + (q >> 3), qw2 = w0 + (q & 7);
      const size_t qp2 = ((size_t)(b * Tv + t) * Hv + qh2) * Wv + qw2;
      oout_h[qp2 * 32 + colw] = val;
    }
  }
}

// ---------------------------------------------------------------------------
extern "C" void kernel_launch(void* const* d_in, const int* in_sizes, int n_in,
                              void* d_out, int out_size, void* d_ws, size_t ws_size,
                              hipStream_t stream) {
  const float* x      = (const float*)d_in[0];
  const float* y      = (const float*)d_in[1];
  const float* qv_w   = (const float*)d_in[2];
  const float* qv_b   = (const float*)d_in[3];
  const float* k_w    = (const float*)d_in[4];
  const float* k_b    = (const float*)d_in[5];
  const float* proj_w = (const float*)d_in[6];
  const float* proj_b = (const float*)d_in[7];
  const float* rpb    = (const float*)d_in[8];
  float* out = (float*)d_out;

  const size_t elems = (size_t)MPOS * 128;        // 8,388,608
  ushort* qbuf = (ushort*)d_ws;                   // 16.8 MB (bf16, head-major)
  ushort* kbuf = qbuf + elems;                    // 16.8 MB
  ushort* vbuf = kbuf + elems;                    // 16.8 MB
  float*  obuf = (float*)(vbuf + elems);          // 33.5 MB (attn out, head-major)
  ushort* wqvT   = (ushort*)(obuf + elems);
  ushort* wkT    = wqvT + 256 * KPAD;
  ushort* wpT_hi = wkT + 128 * KPAD;
  ushort* wpT_lo = wpT_hi + 128 * KPAD;

  preconvert    <<<256,  256, 0, stream>>>(qv_w, k_w, proj_w, wqvT, wkT, wpT_hi, wpT_lo);
  gemm_qvk      <<<1024, 512, 0, stream>>>(x, y, wqvT, wkT, qv_b, k_b, qbuf, vbuf, kbuf);
  na3d_tile     <<<4096, 1024, 0, stream>>>(qbuf, kbuf, vbuf, rpb, obuf);
  gemm_proj_mfma<<<512,  512, 0, stream>>>(obuf, wpT_hi, wpT_lo, proj_b, out);
}

// Round 8
// 242.290 us; speedup vs baseline: 1.3849x; 1.3849x over previous
//
#include <hip/hip_runtime.h>
#include <hip/hip_bf16.h>
#include <hip/hip_fp16.h>
#include <cmath>

// Problem constants
#define Bv   2
#define Tv   8
#define Hv   64
#define Wv   64
#define MPOS (Bv*Tv*Hv*Wv)           // 65536 positions
#define SCALEv 0.17677669529663687f  // 32^-0.5

// Attention tiling: 8x8 queries (one t, one b, one head) per block.
// 3 passes (one per time-slice ut), 196 spatial union positions per pass.
// R8: 512 threads / 8 waves, 61.5 KB LDS -> 2 blocks/CU, VGPR cap 128
// (NO SPILL — R4-R7's launch_bounds(1024,8) forced a 64-reg cap and the
// spill-to-scratch traffic was the mystery 147-557 MB WRITE_SIZE).
// Intermediates remain HEAD-MAJOR [head][pos][32].
#define SPOS  196                    // 14x14 spatial union per time slice
#define SVT   464                    // Vt/P row stride bytes (116 dw == 20 mod 32)
#define NCOLS 232                    // row stride in ushorts

// LDS layout (bytes)
#define KOFF   0                     // K: 208 slots x 64 B (13 x 1KB chunks)
#define VTOFF  13312                 // Vt: 32 x 464 B, XOR-swizzled (d>>3)<<5
#define POFF   28160                 // P : 64 x 464 B (f16 raw -> bf16 exp)
#define RPBOFF 57856                 // 845 f32 (this head's rpb)
#define INVOFF 61248                 // 64 f32 (1/sum)
#define SMEM_BYTES 61504             // 2 blocks/CU (123 KB <= 160 KB)

// GEMM LDS row padding: 136 bf16 = 272 B; 272/4 = 68 dwords == 4 (mod 32)
#define KPAD 136

typedef __attribute__((ext_vector_type(8))) short bf16x8;   // MFMA A/B frag
typedef __attribute__((ext_vector_type(4))) float f32x4;    // MFMA C/D frag

__device__ __forceinline__ unsigned short f2bf16(float x) {
  return __builtin_bit_cast(unsigned short, __float2bfloat16(x));
}
__device__ __forceinline__ float bf2f(unsigned short h) {
  return __uint_as_float((unsigned)h << 16);
}
__device__ __forceinline__ float h2f(unsigned short h) {
  return __half2float(__builtin_bit_cast(__half, h));
}
__device__ __forceinline__ unsigned short f2h(float x) {
  return __builtin_bit_cast(unsigned short, __float2half(x));
}
__device__ __forceinline__ unsigned pk2(float a, float b) {
  return (unsigned)f2bf16(a) | ((unsigned)f2bf16(b) << 16);
}
// async global->LDS, 16B per lane; dest = wave-uniform base + lane*16
__device__ __forceinline__ void gload_lds16(const void* gsrc, void* ldst) {
  __builtin_amdgcn_global_load_lds(
      (const __attribute__((address_space(1))) unsigned int*)gsrc,
      (__attribute__((address_space(3))) unsigned int*)ldst, 16, 0, 0);
}

// ---------------------------------------------------------------------------
// Preconvert weights: transpose to [n][k] bf16 with KPAD row stride.
// ---------------------------------------------------------------------------
__global__ __launch_bounds__(256) void preconvert(
    const float* __restrict__ qv_w, const float* __restrict__ k_w,
    const float* __restrict__ proj_w,
    ushort* __restrict__ wqvT, ushort* __restrict__ wkT,
    ushort* __restrict__ wpT_hi, ushort* __restrict__ wpT_lo) {
  const int id = blockIdx.x * 256 + threadIdx.x;
  if (id < 32768) {                       // qv: n<256, k<128
    const int n = id >> 7, kk = id & 127;
    wqvT[n * KPAD + kk] = f2bf16(qv_w[kk * 256 + n]);
  } else if (id < 49152) {                // k: n<128
    const int j = id - 32768;
    const int n = j >> 7, kk = j & 127;
    wkT[n * KPAD + kk] = f2bf16(k_w[kk * 128 + n]);
  } else {                                // proj: hi/lo split
    const int j = id - 49152;
    const int n = j >> 7, kk = j & 127;
    const float v = proj_w[kk * 128 + n];
    const unsigned short hi = f2bf16(v);
    wpT_hi[n * KPAD + kk] = hi;
    wpT_lo[n * KPAD + kk] = f2bf16(v - bf2f(hi));
  }
}

// ---------------------------------------------------------------------------
// Fused q/v/k projection GEMMs. Grid 1536 x 512thr; seg = bx>>9 (0=q,1=v,2=k).
// Compile-time 8 n-tiles per block (rule #20: NO runtime-bounded C[] loops).
// Outputs HEAD-MAJOR: buf[head][pos][32] bf16.
// ---------------------------------------------------------------------------
__global__ __launch_bounds__(512) void gemm_qvk(
    const float* __restrict__ x, const float* __restrict__ y,
    const ushort* __restrict__ wqvT, const ushort* __restrict__ wkT,
    const float* __restrict__ qv_b, const float* __restrict__ k_b,
    ushort* __restrict__ qbuf, ushort* __restrict__ vbuf,
    ushort* __restrict__ kbuf) {
  __shared__ ushort Ws[128 * KPAD];
  const int tid  = threadIdx.x;
  const int bx   = blockIdx.x;
  const int seg  = bx >> 9;                 // 0=q, 1=v, 2=k
  const int row0 = (bx & 511) * 128;

  const float*  A    = (seg == 2) ? y : x;
  const ushort* W    = (seg == 0) ? wqvT : (seg == 1) ? wqvT + 128 * KPAD : wkT;
  const float*  bias = (seg == 0) ? qv_b : (seg == 1) ? qv_b + 128 : k_b;
  ushort*       outp = (seg == 0) ? qbuf : (seg == 1) ? vbuf : kbuf;
  const float   scale = (seg == 0) ? SCALEv : 1.0f;

  {
    const uint4* wg = (const uint4*)W;
    for (int i = tid; i < 2176; i += 512)
      gload_lds16(wg + i, (uint4*)Ws + i);
  }

  const int wv = tid >> 6, lane = tid & 63, quad = lane >> 4, l16 = lane & 15;
  const int arow = row0 + wv * 16 + l16;

  bf16x8 af[4];
#pragma unroll
  for (int kk = 0; kk < 4; ++kk) {
    const float4* ap = (const float4*)(A + (size_t)arow * 128 + kk * 32 + quad * 8);
    const float4 a = ap[0], b2 = ap[1];
    af[kk] = __builtin_bit_cast(bf16x8,
        make_uint4(pk2(a.x, a.y), pk2(a.z, a.w), pk2(b2.x, b2.y), pk2(b2.z, b2.w)));
  }
  __syncthreads();

  f32x4 C[8];
#pragma unroll
  for (int nt = 0; nt < 8; ++nt) C[nt] = (f32x4){0.f, 0.f, 0.f, 0.f};

#pragma unroll
  for (int kk = 0; kk < 4; ++kk) {
#pragma unroll
    for (int nt = 0; nt < 8; ++nt) {
      const bf16x8 b2 = *(const bf16x8*)(Ws + (nt * 16 + l16) * KPAD + kk * 32 + quad * 8);
      C[nt] = __builtin_amdgcn_mfma_f32_16x16x32_bf16(af[kk], b2, C[nt], 0, 0, 0);
    }
  }

#pragma unroll
  for (int nt = 0; nt < 8; ++nt) {
    const int col = nt * 16 + l16;
    const float bv = bias[col];
#pragma unroll
    for (int r2 = 0; r2 < 4; ++r2) {
      const size_t row = row0 + wv * 16 + quad * 4 + r2;
      outp[(size_t)(col >> 5) * MPOS * 32 + row * 32 + (col & 31)] =
          f2bf16((C[nt][r2] + bv) * scale);
    }
  }
}

// ---------------------------------------------------------------------------
// Output projection, bf16x3 (fp32-accurate). obuf is HEAD-MAJOR; the kk-th
// 32-wide K-block of the proj GEMM == head kk exactly.
// ---------------------------------------------------------------------------
__global__ __launch_bounds__(512) void gemm_proj_mfma(
    const float* __restrict__ o, const ushort* __restrict__ wpT_hi,
    const ushort* __restrict__ wpT_lo, const float* __restrict__ proj_b,
    float* __restrict__ out) {
  __shared__ ushort Wh[128 * KPAD];
  __shared__ ushort Wl[128 * KPAD];
  const int tid  = threadIdx.x;
  const int row0 = blockIdx.x * 128;
  {
    const uint4* wgh = (const uint4*)wpT_hi;
    const uint4* wgl = (const uint4*)wpT_lo;
    for (int i = tid; i < 2176; i += 512) {
      gload_lds16(wgh + i, (uint4*)Wh + i);
      gload_lds16(wgl + i, (uint4*)Wl + i);
    }
  }

  const int wv = tid >> 6, lane = tid & 63, quad = lane >> 4, l16 = lane & 15;
  const int arow = row0 + wv * 16 + l16;

  bf16x8 ah[4], al[4];
#pragma unroll
  for (int kk = 0; kk < 4; ++kk) {
    const float4* ap =
        (const float4*)(o + (size_t)kk * MPOS * 32 + (size_t)arow * 32 + quad * 8);
    const float4 a = ap[0], b2 = ap[1];
    const float vs[8] = {a.x, a.y, a.z, a.w, b2.x, b2.y, b2.z, b2.w};
    unsigned hw[4], lw[4];
#pragma unroll
    for (int e = 0; e < 4; ++e) {
      const unsigned short h0 = f2bf16(vs[2 * e]);
      const unsigned short h1 = f2bf16(vs[2 * e + 1]);
      hw[e] = (unsigned)h0 | ((unsigned)h1 << 16);
      lw[e] = (unsigned)f2bf16(vs[2 * e] - bf2f(h0)) |
              ((unsigned)f2bf16(vs[2 * e + 1] - bf2f(h1)) << 16);
    }
    ah[kk] = __builtin_bit_cast(bf16x8, make_uint4(hw[0], hw[1], hw[2], hw[3]));
    al[kk] = __builtin_bit_cast(bf16x8, make_uint4(lw[0], lw[1], lw[2], lw[3]));
  }
  __syncthreads();

  f32x4 C[8];
#pragma unroll
  for (int nt = 0; nt < 8; ++nt) C[nt] = (f32x4){0.f, 0.f, 0.f, 0.f};

#pragma unroll
  for (int kk = 0; kk < 4; ++kk) {
#pragma unroll
    for (int nt = 0; nt < 8; ++nt) {
      const int boff = (nt * 16 + l16) * KPAD + kk * 32 + quad * 8;
      const bf16x8 bh = *(const bf16x8*)(Wh + boff);
      const bf16x8 bl = *(const bf16x8*)(Wl + boff);
      C[nt] = __builtin_amdgcn_mfma_f32_16x16x32_bf16(ah[kk], bh, C[nt], 0, 0, 0);
      C[nt] = __builtin_amdgcn_mfma_f32_16x16x32_bf16(ah[kk], bl, C[nt], 0, 0, 0);
      C[nt] = __builtin_amdgcn_mfma_f32_16x16x32_bf16(al[kk], bh, C[nt], 0, 0, 0);
    }
  }

#pragma unroll
  for (int nt = 0; nt < 8; ++nt) {
    const int col = nt * 16 + l16;
    const float bv = proj_b[col];
#pragma unroll
    for (int r2 = 0; r2 < 4; ++r2) {
      const size_t row = row0 + wv * 16 + quad * 4 + r2;
      out[row * 128 + col] = C[nt][r2] + bv;
    }
  }
}

// ---------------------------------------------------------------------------
// MFMA NA3D attention. Block = 8x8 query tile (one b,t,head), 512 thr/8 waves.
// 3 passes (one per ut), K via global_load_lds, 61.5 KB LDS -> 2 blocks/CU.
// Each AV wave owns all 7 kt (no partial-combine scratch). Head-major I/O.
// ---------------------------------------------------------------------------
__global__ __launch_bounds__(512, 4)
void na3d_tile(
    const ushort* __restrict__ qin,
    const ushort* __restrict__ kin,
    const ushort* __restrict__ vin,
    const float* __restrict__ rpb,
    float* __restrict__ oout) {
  __shared__ __align__(16) unsigned char smem[SMEM_BYTES];

  const int tid  = threadIdx.x;
  const int wv   = tid >> 6;          // 0..7
  const int lane = tid & 63;
  const int quad = lane >> 4;
  const int l16  = lane & 15;

  const int bx   = blockIdx.x;
  const int head = bx & 3;
  const int tile = bx >> 2;
  const int w0 = (tile & 7) << 3;
  const int h0 = ((tile >> 3) & 7) << 3;
  const int t  = (tile >> 6) & 7;
  const int b  = tile >> 9;

  const int st  = min(max(t - 1, 0), Tv - 3);
  const int u_h = min(max(h0 - 3, 0), Hv - 14);
  const int u_w = min(max(w0 - 3, 0), Wv - 14);
  const int rt_b = st - t + 2;   // 0..2

  // head-major bases
  const ushort* qin_h = qin + (size_t)head * MPOS * 32;
  const uint4*  kin_h = (const uint4*)kin + (size_t)head * MPOS * 4;
  const uint4*  vin_h = (const uint4*)vin + (size_t)head * MPOS * 4;

  // Q A-frag (pass-invariant)
  const int mtile = wv & 3;
  bf16x8 afrag;
  {
    const int q_a  = mtile * 16 + l16;
    const int qh_a = h0 + (q_a >> 3), qw_a = w0 + (q_a & 7);
    const size_t qpos_a = ((size_t)(b * Tv + t) * Hv + qh_a) * Wv + qw_a;
    afrag = *(const bf16x8*)(qin_h + qpos_a * 32 + quad * 8);
  }
  // rpb -> LDS (two strided chunks at 512 threads)
  {
    float r0 = 0.f, r1 = 0.f;
    if (tid < 845) r0 = rpb[head * 845 + tid];
    if (tid < 333) r1 = rpb[head * 845 + tid + 512];
    if (tid < 845) ((float*)(smem + RPBOFF))[tid] = r0;
    if (tid < 333) ((float*)(smem + RPBOFF))[tid + 512] = r1;
  }

  // softmax geometry (pass-invariant); 8 threads per query row
  const int qs = tid >> 3, l8s = tid & 7;
  const int qh_s = h0 + (qs >> 3), qw_s = w0 + (qs & 7);
  const int sh_s = min(max(qh_s - 3, 0), Hv - 7);
  const int sw_s = min(max(qw_s - 3, 0), Wv - 7);
  const int dh_s = sh_s - u_h, dw_s = sw_s - u_w;          // [0,7]
  const int rh0 = sh_s - qh_s + 6, rw0 = sw_s - qw_s + 6;  // [0,6]

  // AV wave mapping: 4 mtA x 2 ntA; each wave does ALL 7 kt
  const int mtA = wv >> 1, ntA = wv & 1;
  const int dcol = ntA * 16 + l16;
  const unsigned vsw = ((unsigned)(dcol >> 3) & 3u) << 5;

  f32x4 o = {0.f, 0.f, 0.f, 0.f};
  float sum = 0.f;
  uint4 vv0, vv1;

  // V chunk decode (pass-invariant; 784 uint4 chunks over 512 threads)
  const int vp0 = tid >> 2, vc0 = tid & 3;
  const int vr0 = vp0 / 14;
  const unsigned vsp0 = ((u_h + vr0) * Wv + (u_w + (vp0 - vr0 * 14))) * 4 + vc0;
  const int j1 = tid + 512;                 // valid when tid < 272
  const int vp1 = j1 >> 2, vc1 = j1 & 3;
  const int vr1 = vp1 / 14;
  const unsigned vsp1 = ((u_h + vr1) * Wv + (u_w + (vp1 - vr1 * 14))) * 4 + vc1;

  // prologue: issue V + K for pass 0
  {
    const unsigned tbase = (unsigned)(b * Tv + st) * (Hv * Wv * 4);
    vv0 = vin_h[tbase + vsp0];
    if (tid < 272) vv1 = vin_h[tbase + vsp1];
    for (int ch = wv; ch < 13; ch += 8) {
      const int m = ch * 64 + lane;
      const int pos = min(m >> 2, SPOS - 1);
      const int c = ((m & 3) - (pos >> 2)) & 3;
      const int rh = pos / 14;
      const unsigned sp = ((u_h + rh) * Wv + (u_w + (pos - rh * 14))) * 4 + c;
      gload_lds16(kin_h + tbase + sp, smem + KOFF + ch * 1024 + lane * 16);
    }
  }

#pragma unroll 1
  for (int pass = 0; pass < 3; ++pass) {
    // ---- V repack -> Vt (XOR-swizzled by (d>>3)<<5) ----
    {
      const unsigned sw0 = (unsigned)vc0 << 5;
      const unsigned v4[4] = {vv0.x, vv0.y, vv0.z, vv0.w};
#pragma unroll
      for (int m2 = 0; m2 < 4; ++m2) {
        const int d0 = 8 * vc0 + 2 * m2;
        const unsigned base = (unsigned)d0 * SVT + (unsigned)vp0 * 2;
        *(ushort*)(smem + VTOFF + (base ^ sw0))         = (ushort)(v4[m2] & 0xffffu);
        *(ushort*)(smem + VTOFF + ((base + SVT) ^ sw0)) = (ushort)(v4[m2] >> 16);
      }
      if (tid < 272) {
        const unsigned sw1 = (unsigned)vc1 << 5;
        const unsigned w4[4] = {vv1.x, vv1.y, vv1.z, vv1.w};
#pragma unroll
        for (int m2 = 0; m2 < 4; ++m2) {
          const int d0 = 8 * vc1 + 2 * m2;
          const unsigned base = (unsigned)d0 * SVT + (unsigned)vp1 * 2;
          *(ushort*)(smem + VTOFF + (base ^ sw1))         = (ushort)(w4[m2] & 0xffffu);
          *(ushort*)(smem + VTOFF + ((base + SVT) ^ sw1)) = (ushort)(w4[m2] >> 16);
        }
      }
    }
    // Vt tail zero: cols 196..231 (18 dwords x 32 rows), pass 0 only
    if (pass == 0) {
      for (int i = tid; i < 576; i += 512) {
        const int d = i / 18, jj = i - d * 18;
        const unsigned base = (unsigned)d * SVT + 392u + (unsigned)jj * 4;
        *(unsigned*)(smem + VTOFF + (base ^ (((unsigned)d >> 3) << 5))) = 0u;
      }
    }
    __syncthreads();   // (A) K + Vt ready (vmcnt drained by barrier)

    // ---- QK: 13 tiles over 2 wave-groups, raw f16 scores -> P ----
    {
      ushort* ph = (ushort*)(smem + POFF);
      for (int nt = (wv >> 2); nt < 13; nt += 2) {
        const int u = nt * 16 + l16;
        const int slot = (quad + (u >> 2)) & 3;
        const bf16x8 bfrag = *(const bf16x8*)(smem + KOFF + u * 64 + slot * 16);
        f32x4 c = {0.f, 0.f, 0.f, 0.f};
        c = __builtin_amdgcn_mfma_f32_16x16x32_bf16(afrag, bfrag, c, 0, 0, 0);
#pragma unroll
        for (int r2 = 0; r2 < 4; ++r2) {
          const int qrow = mtile * 16 + quad * 4 + r2;
          ph[qrow * NCOLS + u] = f2h(c[r2]);
        }
      }
    }
    __syncthreads();   // (B) P raw ready

    // ---- softmax: 49 valid / query (7 runs of 7). 8 threads/row.
    // read+exp -> zero -> scatter; row touched only by its own 8-lane group
    // (same wave) -> wave-ordered, no intra barriers. ----
    {
      const ushort* Ps = (const ushort*)(smem + POFF) + qs * NCOLS;
      const float* rpb_l = (const float*)(smem + RPBOFF) + (rt_b + pass) * 169;
      float ex[7];
      int uu[7];
#pragma unroll
      for (int k = 0; k < 7; ++k) {
        const int e = l8s + 8 * k;
        const int a = (e * 37) >> 8;             // e/7 for e<64
        const int bb = e - 7 * a;
        uu[k] = (dh_s + a) * 14 + dw_s + bb;
        if (e < 49) {
          const float s = h2f(Ps[uu[k]]) + rpb_l[(rh0 + a) * 13 + rw0 + bb];
          ex[k] = __expf(s);
          sum += ex[k];
        }
      }
      if (pass == 2) {
        float sm = sum;
        sm += __shfl_xor(sm, 1);
        sm += __shfl_xor(sm, 2);
        sm += __shfl_xor(sm, 4);
        if (l8s == 0) ((float*)(smem + INVOFF))[qs] = 1.0f / sm;
      }
      __builtin_amdgcn_sched_barrier(0);         // reads before zeros
      {
        uint4* Pv = (uint4*)(smem + POFF + (size_t)qs * SVT);
#pragma unroll
        for (int c = 0; c < 4; ++c) {
          const int idx = l8s + 8 * c;
          if (idx < 29) Pv[idx] = make_uint4(0u, 0u, 0u, 0u);
        }
      }
      __builtin_amdgcn_sched_barrier(0);         // zeros before scatter
      ushort* Pr = (ushort*)(smem + POFF) + qs * NCOLS;
#pragma unroll
      for (int k = 0; k < 7; ++k) {
        const int e = l8s + 8 * k;
        if (e < 49) Pr[uu[k]] = f2bf16(ex[k]);
      }
    }
    __syncthreads();   // (E) P ready

    // ---- issue next pass's V + K (drains at barrier F, hidden by AV) ----
    if (pass < 2) {
      const unsigned tbase = (unsigned)(b * Tv + st + pass + 1) * (Hv * Wv * 4);
      vv0 = vin_h[tbase + vsp0];
      if (tid < 272) vv1 = vin_h[tbase + vsp1];
      for (int ch = wv; ch < 13; ch += 8) {
        const int m = ch * 64 + lane;
        const int pos = min(m >> 2, SPOS - 1);
        const int c = ((m & 3) - (pos >> 2)) & 3;
        const int rh = pos / 14;
        const unsigned sp = ((u_h + rh) * Wv + (u_w + (pos - rh * 14))) * 4 + c;
        gload_lds16(kin_h + tbase + sp, smem + KOFF + ch * 1024 + lane * 16);
      }
    }

    // ---- AV: each wave all 7 kt, accumulate across passes ----
    {
      const unsigned char* Abase = smem + POFF + (size_t)(mtA * 16 + l16) * SVT;
      const unsigned vlocal = (unsigned)dcol * SVT;
#pragma unroll
      for (int kt = 0; kt < 7; ++kt) {
        const bf16x8 a  = *(const bf16x8*)(Abase + kt * 64 + quad * 16);
        const bf16x8 bb = *(const bf16x8*)(smem + VTOFF +
                            ((vlocal + kt * 64 + quad * 16) ^ vsw));
        o = __builtin_amdgcn_mfma_f32_16x16x32_bf16(a, bb, o, 0, 0, 0);
      }
    }
    if (pass < 2) __syncthreads();   // (F) AV reads done -> restage Vt/K/P
  }

  // ---- epilogue: normalize + store (same-block 64 B chunks, L2-coalesced;
  // R3 proved this pattern writes at exactly ideal volume) ----
  {
    float* oout_h = oout + (size_t)head * MPOS * 32;
    const float* invArr = (const float*)(smem + INVOFF);
#pragma unroll
    for (int r2 = 0; r2 < 4; ++r2) {
      const int qrow = mtA * 16 + quad * 4 + r2;
      const float val = o[r2] * invArr[qrow];
      const int qh2 = h0 + (qrow >> 3), qw2 = w0 + (qrow & 7);
      const size_t qp2 = ((size_t)(b * Tv + t) * Hv + qh2) * Wv + qw2;
      oout_h[qp2 * 32 + dcol] = val;
    }
  }
}

// ---------------------------------------------------------------------------
extern "C" void kernel_launch(void* const* d_in, const int* in_sizes, int n_in,
                              void* d_out, int out_size, void* d_ws, size_t ws_size,
                              hipStream_t stream) {
  const float* x      = (const float*)d_in[0];
  const float* y      = (const float*)d_in[1];
  const float* qv_w   = (const float*)d_in[2];
  const float* qv_b   = (const float*)d_in[3];
  const float* k_w    = (const float*)d_in[4];
  const float* k_b    = (const float*)d_in[5];
  const float* proj_w = (const float*)d_in[6];
  const float* proj_b = (const float*)d_in[7];
  const float* rpb    = (const float*)d_in[8];
  float* out = (float*)d_out;

  const size_t elems = (size_t)MPOS * 128;        // 8,388,608
  ushort* qbuf = (ushort*)d_ws;                   // 16.8 MB (bf16, head-major)
  ushort* kbuf = qbuf + elems;                    // 16.8 MB
  ushort* vbuf = kbuf + elems;                    // 16.8 MB
  float*  obuf = (float*)(vbuf + elems);          // 33.5 MB (attn out, head-major)
  ushort* wqvT   = (ushort*)(obuf + elems);
  ushort* wkT    = wqvT + 256 * KPAD;
  ushort* wpT_hi = wkT + 128 * KPAD;
  ushort* wpT_lo = wpT_hi + 128 * KPAD;

  preconvert    <<<256,  256, 0, stream>>>(qv_w, k_w, proj_w, wqvT, wkT, wpT_hi, wpT_lo);
  gemm_qvk      <<<1536, 512, 0, stream>>>(x, y, wqvT, wkT, qv_b, k_b, qbuf, vbuf, kbuf);
  na3d_tile     <<<4096, 512, 0, stream>>>(qbuf, kbuf, vbuf, rpb, obuf);
  gemm_proj_mfma<<<512,  512, 0, stream>>>(obuf, wpT_hi, wpT_lo, proj_b, out);
}

// Round 9
// 241.717 us; speedup vs baseline: 1.3881x; 1.0024x over previous
//
#include <hip/hip_runtime.h>
#include <hip/hip_bf16.h>
#include <hip/hip_fp16.h>
#include <cmath>

// Problem constants
#define Bv   2
#define Tv   8
#define Hv   64
#define Wv   64
#define MPOS (Bv*Tv*Hv*Wv)           // 65536 positions
#define SCALEv 0.17677669529663687f  // 32^-0.5

// Attention tiling: 8x8 queries (one t, one b, one head) per block.
// 3 passes (one per time-slice). R9: u-grid is 14x16 (u = rh*16+rw, 224 slots,
// rw>=14 dead). V is stored PRE-TRANSPOSED by gemm_qvk as planes
// vbufT[head*16+bt][d(32)][spatial(4096)] so na3d stages Vt via pure
// global_load_lds (linear dest + swizzle-inverted per-lane SOURCE, rule #21).
// Vt double-buffered; no in-kernel repack, no tail zeros.
#define SVT   464                    // P row stride bytes (116 dw == 20 mod 32)
#define NCOLS 232                    // P row stride in ushorts

// LDS layout (bytes)
#define KOFF   0                     // K: 224 slots x 64 B (14 x 1KB chunks)
#define VT0    14336                 // Vt buf0: 32 d x 512 B (XOR (d&7)<<4)
#define VT1    30720                 // Vt buf1
#define POFF   47104                 // P : 64 x 464 B (f16 raw -> bf16 exp)
#define RPBOFF 76800                 // 845 f32 (this head's rpb)
#define INVOFF 80180                 // 64 f32 (1/sum)
#define SMEM_BYTES 80448             // <= 81920 -> 2 blocks/CU (4 waves/SIMD)

// GEMM LDS row padding: 136 bf16 = 272 B; 272/4 = 68 dwords == 4 (mod 32)
#define KPAD 136

typedef __attribute__((ext_vector_type(8))) short bf16x8;   // MFMA A/B frag
typedef __attribute__((ext_vector_type(4))) float f32x4;    // MFMA C/D frag

__device__ __forceinline__ unsigned short f2bf16(float x) {
  return __builtin_bit_cast(unsigned short, __float2bfloat16(x));
}
__device__ __forceinline__ float bf2f(unsigned short h) {
  return __uint_as_float((unsigned)h << 16);
}
__device__ __forceinline__ float h2f(unsigned short h) {
  return __half2float(__builtin_bit_cast(__half, h));
}
__device__ __forceinline__ unsigned short f2h(float x) {
  return __builtin_bit_cast(unsigned short, __float2half(x));
}
__device__ __forceinline__ unsigned pk2(float a, float b) {
  return (unsigned)f2bf16(a) | ((unsigned)f2bf16(b) << 16);
}
// async global->LDS, 16B per lane; dest = wave-uniform base + lane*16
__device__ __forceinline__ void gload_lds16(const void* gsrc, void* ldst) {
  __builtin_amdgcn_global_load_lds(
      (const __attribute__((address_space(1))) unsigned int*)gsrc,
      (__attribute__((address_space(3))) unsigned int*)ldst, 16, 0, 0);
}

// ---------------------------------------------------------------------------
// Preconvert weights: transpose to [n][k] bf16 with KPAD row stride.
// ---------------------------------------------------------------------------
__global__ __launch_bounds__(256) void preconvert(
    const float* __restrict__ qv_w, const float* __restrict__ k_w,
    const float* __restrict__ proj_w,
    ushort* __restrict__ wqvT, ushort* __restrict__ wkT,
    ushort* __restrict__ wpT_hi, ushort* __restrict__ wpT_lo) {
  const int id = blockIdx.x * 256 + threadIdx.x;
  if (id < 32768) {                       // qv: n<256, k<128
    const int n = id >> 7, kk = id & 127;
    wqvT[n * KPAD + kk] = f2bf16(qv_w[kk * 256 + n]);
  } else if (id < 49152) {                // k: n<128
    const int j = id - 32768;
    const int n = j >> 7, kk = j & 127;
    wkT[n * KPAD + kk] = f2bf16(k_w[kk * 128 + n]);
  } else {                                // proj: hi/lo split
    const int j = id - 49152;
    const int n = j >> 7, kk = j & 127;
    const float v = proj_w[kk * 128 + n];
    const unsigned short hi = f2bf16(v);
    wpT_hi[n * KPAD + kk] = hi;
    wpT_lo[n * KPAD + kk] = f2bf16(v - bf2f(hi));
  }
}

// ---------------------------------------------------------------------------
// Fused q/v/k projection GEMMs. Grid 1536 x 512thr; seg = bx>>9 (0=q,1=v,2=k).
// q/k outputs HEAD-MAJOR [head][pos][32]; v output PRE-TRANSPOSED planes
// vbufT[(head*16+bt)*32 + d][sp] (b64 stores pack the 4 r2-consecutive pos).
// ---------------------------------------------------------------------------
__global__ __launch_bounds__(512) void gemm_qvk(
    const float* __restrict__ x, const float* __restrict__ y,
    const ushort* __restrict__ wqvT, const ushort* __restrict__ wkT,
    const float* __restrict__ qv_b, const float* __restrict__ k_b,
    ushort* __restrict__ qbuf, ushort* __restrict__ vbuf,
    ushort* __restrict__ kbuf) {
  __shared__ ushort Ws[128 * KPAD];
  const int tid  = threadIdx.x;
  const int bx   = blockIdx.x;
  const int seg  = bx >> 9;                 // 0=q, 1=v, 2=k
  const int row0 = (bx & 511) * 128;

  const float*  A    = (seg == 2) ? y : x;
  const ushort* W    = (seg == 0) ? wqvT : (seg == 1) ? wqvT + 128 * KPAD : wkT;
  const float*  bias = (seg == 0) ? qv_b : (seg == 1) ? qv_b + 128 : k_b;
  const float   scale = (seg == 0) ? SCALEv : 1.0f;

  {
    const uint4* wg = (const uint4*)W;
    for (int i = tid; i < 2176; i += 512)
      gload_lds16(wg + i, (uint4*)Ws + i);
  }

  const int wv = tid >> 6, lane = tid & 63, quad = lane >> 4, l16 = lane & 15;
  const int arow = row0 + wv * 16 + l16;

  bf16x8 af[4];
#pragma unroll
  for (int kk = 0; kk < 4; ++kk) {
    const float4* ap = (const float4*)(A + (size_t)arow * 128 + kk * 32 + quad * 8);
    const float4 a = ap[0], b2 = ap[1];
    af[kk] = __builtin_bit_cast(bf16x8,
        make_uint4(pk2(a.x, a.y), pk2(a.z, a.w), pk2(b2.x, b2.y), pk2(b2.z, b2.w)));
  }
  __syncthreads();

  f32x4 C[8];
#pragma unroll
  for (int nt = 0; nt < 8; ++nt) C[nt] = (f32x4){0.f, 0.f, 0.f, 0.f};

#pragma unroll
  for (int kk = 0; kk < 4; ++kk) {
#pragma unroll
    for (int nt = 0; nt < 8; ++nt) {
      const bf16x8 b2 = *(const bf16x8*)(Ws + (nt * 16 + l16) * KPAD + kk * 32 + quad * 8);
      C[nt] = __builtin_amdgcn_mfma_f32_16x16x32_bf16(af[kk], b2, C[nt], 0, 0, 0);
    }
  }

  if (seg == 1) {
    // V: transposed-plane store. Thread holds 4 consecutive positions (r2).
    const int p0 = row0 + wv * 16 + quad * 4;
    const int bt = p0 >> 12, sp = p0 & 4095;
#pragma unroll
    for (int nt = 0; nt < 8; ++nt) {
      const int d = nt * 16 + l16;            // 0..127
      const float bv = bias[d];
      const ushort4 pk4 = make_ushort4(
          f2bf16(C[nt][0] + bv), f2bf16(C[nt][1] + bv),
          f2bf16(C[nt][2] + bv), f2bf16(C[nt][3] + bv));
      *(ushort4*)(vbuf + (size_t)(((d >> 5) * 16 + bt) * 32 + (d & 31)) * 4096 + sp) = pk4;
    }
  } else {
    ushort* outp = (seg == 0) ? qbuf : kbuf;
#pragma unroll
    for (int nt = 0; nt < 8; ++nt) {
      const int col = nt * 16 + l16;
      const float bv = bias[col];
#pragma unroll
      for (int r2 = 0; r2 < 4; ++r2) {
        const size_t row = row0 + wv * 16 + quad * 4 + r2;
        outp[(size_t)(col >> 5) * MPOS * 32 + row * 32 + (col & 31)] =
            f2bf16((C[nt][r2] + bv) * scale);
      }
    }
  }
}

// ---------------------------------------------------------------------------
// Output projection, bf16x3 (fp32-accurate). obuf is HEAD-MAJOR.
// ---------------------------------------------------------------------------
__global__ __launch_bounds__(512) void gemm_proj_mfma(
    const float* __restrict__ o, const ushort* __restrict__ wpT_hi,
    const ushort* __restrict__ wpT_lo, const float* __restrict__ proj_b,
    float* __restrict__ out) {
  __shared__ ushort Wh[128 * KPAD];
  __shared__ ushort Wl[128 * KPAD];
  const int tid  = threadIdx.x;
  const int row0 = blockIdx.x * 128;
  {
    const uint4* wgh = (const uint4*)wpT_hi;
    const uint4* wgl = (const uint4*)wpT_lo;
    for (int i = tid; i < 2176; i += 512) {
      gload_lds16(wgh + i, (uint4*)Wh + i);
      gload_lds16(wgl + i, (uint4*)Wl + i);
    }
  }

  const int wv = tid >> 6, lane = tid & 63, quad = lane >> 4, l16 = lane & 15;
  const int arow = row0 + wv * 16 + l16;

  bf16x8 ah[4], al[4];
#pragma unroll
  for (int kk = 0; kk < 4; ++kk) {
    const float4* ap =
        (const float4*)(o + (size_t)kk * MPOS * 32 + (size_t)arow * 32 + quad * 8);
    const float4 a = ap[0], b2 = ap[1];
    const float vs[8] = {a.x, a.y, a.z, a.w, b2.x, b2.y, b2.z, b2.w};
    unsigned hw[4], lw[4];
#pragma unroll
    for (int e = 0; e < 4; ++e) {
      const unsigned short h0 = f2bf16(vs[2 * e]);
      const unsigned short h1 = f2bf16(vs[2 * e + 1]);
      hw[e] = (unsigned)h0 | ((unsigned)h1 << 16);
      lw[e] = (unsigned)f2bf16(vs[2 * e] - bf2f(h0)) |
              ((unsigned)f2bf16(vs[2 * e + 1] - bf2f(h1)) << 16);
    }
    ah[kk] = __builtin_bit_cast(bf16x8, make_uint4(hw[0], hw[1], hw[2], hw[3]));
    al[kk] = __builtin_bit_cast(bf16x8, make_uint4(lw[0], lw[1], lw[2], lw[3]));
  }
  __syncthreads();

  f32x4 C[8];
#pragma unroll
  for (int nt = 0; nt < 8; ++nt) C[nt] = (f32x4){0.f, 0.f, 0.f, 0.f};

#pragma unroll
  for (int kk = 0; kk < 4; ++kk) {
#pragma unroll
    for (int nt = 0; nt < 8; ++nt) {
      const int boff = (nt * 16 + l16) * KPAD + kk * 32 + quad * 8;
      const bf16x8 bh = *(const bf16x8*)(Wh + boff);
      const bf16x8 bl = *(const bf16x8*)(Wl + boff);
      C[nt] = __builtin_amdgcn_mfma_f32_16x16x32_bf16(ah[kk], bh, C[nt], 0, 0, 0);
      C[nt] = __builtin_amdgcn_mfma_f32_16x16x32_bf16(ah[kk], bl, C[nt], 0, 0, 0);
      C[nt] = __builtin_amdgcn_mfma_f32_16x16x32_bf16(al[kk], bh, C[nt], 0, 0, 0);
    }
  }

#pragma unroll
  for (int nt = 0; nt < 8; ++nt) {
    const int col = nt * 16 + l16;
    const float bv = proj_b[col];
#pragma unroll
    for (int r2 = 0; r2 < 4; ++r2) {
      const size_t row = row0 + wv * 16 + quad * 4 + r2;
      out[row * 128 + col] = C[nt][r2] + bv;
    }
  }
}

// ---------------------------------------------------------------------------
// MFMA NA3D attention. Block = 8x8 query tile (one b,t,head), 512 thr/8 waves.
// 3 passes; K + Vt both staged by global_load_lds; Vt double-buffered.
// 80.4 KB LDS -> 2 blocks/CU. 3 barriers/pass.
// ---------------------------------------------------------------------------
__global__ __launch_bounds__(512, 4)
void na3d_tile(
    const ushort* __restrict__ qin,
    const ushort* __restrict__ kin,
    const ushort* __restrict__ vin,     // TRANSPOSED planes [h*16+bt][32][4096]
    const float* __restrict__ rpb,
    float* __restrict__ oout) {
  __shared__ __align__(16) unsigned char smem[SMEM_BYTES];

  const int tid  = threadIdx.x;
  const int wv   = tid >> 6;          // 0..7
  const int lane = tid & 63;
  const int quad = lane >> 4;
  const int l16  = lane & 15;

  const int bx   = blockIdx.x;
  const int head = bx & 3;
  const int tile = bx >> 2;
  const int w0 = (tile & 7) << 3;
  const int h0 = ((tile >> 3) & 7) << 3;
  const int t  = (tile >> 6) & 7;
  const int b  = tile >> 9;

  const int st  = min(max(t - 1, 0), Tv - 3);
  const int u_h = min(max(h0 - 3, 0), Hv - 14);
  const int u_w = min(max(w0 - 3, 0), Wv - 14);
  const int rt_b = st - t + 2;   // 0..2

  // head-major bases
  const ushort* qin_h = qin + (size_t)head * MPOS * 32;
  const uint4*  kin_h = (const uint4*)kin + (size_t)head * MPOS * 4;

  // Q A-frag (pass-invariant)
  const int mtile = wv & 3;
  bf16x8 afrag;
  {
    const int q_a  = mtile * 16 + l16;
    const int qh_a = h0 + (q_a >> 3), qw_a = w0 + (q_a & 7);
    const size_t qpos_a = ((size_t)(b * Tv + t) * Hv + qh_a) * Wv + qw_a;
    afrag = *(const bf16x8*)(qin_h + qpos_a * 32 + quad * 8);
  }
  // rpb -> LDS
  {
    float r0 = 0.f, r1 = 0.f;
    if (tid < 845) r0 = rpb[head * 845 + tid];
    if (tid < 333) r1 = rpb[head * 845 + tid + 512];
    if (tid < 845) ((float*)(smem + RPBOFF))[tid] = r0;
    if (tid < 333) ((float*)(smem + RPBOFF))[tid + 512] = r1;
  }

  // softmax geometry (pass-invariant); 8 threads per query row
  const int qs = tid >> 3, l8s = tid & 7;
  const int qh_s = h0 + (qs >> 3), qw_s = w0 + (qs & 7);
  const int sh_s = min(max(qh_s - 3, 0), Hv - 7);
  const int sw_s = min(max(qw_s - 3, 0), Wv - 7);
  const int dh_s = sh_s - u_h, dw_s = sw_s - u_w;          // [0,7]
  const int rh0 = sh_s - qh_s + 6, rw0 = sw_s - qw_s + 6;  // [0,6]

  // AV wave mapping: 4 mtA x 2 ntA; each wave does all 7 kt
  const int mtA = wv >> 1, ntA = wv & 1;
  const int dcol = ntA * 16 + l16;
  const unsigned vbase = (unsigned)dcol * 512;
  const unsigned vsw = ((unsigned)dcol & 7u) << 4;

  // K staging decode (pass-invariant): 14 chunks of 1 KB; slot-swizzled src.
  // u-grid: pos = rh*16 + rw (rw>=14 dead, clamped to 13 = dup garbage).
  unsigned ksp[2]; int kch[2]; int nk = 0;
  for (int ch = wv; ch < 14; ch += 8) {
    const int m = ch * 64 + lane;
    const int pos = m >> 2;
    const int c = ((m & 3) - (pos >> 2)) & 3;
    const int rh = pos >> 4, rw = min(pos & 15, 13);
    ksp[nk] = ((u_h + rh) * Wv + (u_w + rw)) * 4 + c;
    kch[nk] = ch;
    ++nk;
  }
  // V staging decode (pass-invariant): 1024 chunks of 16 B into a linear
  // dest; data index block blk = (m&31) XOR (d&7)  (read applies same XOR).
  unsigned vofs[2];
#pragma unroll
  for (int it = 0; it < 2; ++it) {
    const int i = tid + it * 512;
    const int d = i >> 5;
    const int blk = (i & 31) ^ (d & 7);
    const int rh = blk >> 1, rw0b = (blk & 1) << 3;
    vofs[it] = (unsigned)d * 4096 + (u_h + rh) * 64 + (u_w + rw0b);
  }

  f32x4 o = {0.f, 0.f, 0.f, 0.f};
  float sum = 0.f;

  // prologue: issue K + V(buf0) for pass 0
  {
    const unsigned tb_k = (unsigned)(b * Tv + st) * (Hv * Wv * 4);
    for (int s = 0; s < nk; ++s)
      gload_lds16(kin_h + tb_k + ksp[s], smem + KOFF + kch[s] * 1024 + lane * 16);
    const ushort* vpl = vin + (size_t)(head * 16 + b * Tv + st) * 32 * 4096;
#pragma unroll
    for (int it = 0; it < 2; ++it)
      gload_lds16(vpl + vofs[it], smem + VT0 + (tid + it * 512) * 16);
  }

#pragma unroll 1
  for (int pass = 0; pass < 3; ++pass) {
    __syncthreads();   // (1) K+Vt(pass) staged; P free (prev AV done)

    // ---- QK: 14 tiles over 2 wave-groups, raw f16 scores -> P ----
    {
      ushort* ph = (ushort*)(smem + POFF);
      for (int nt = (wv >> 2); nt < 14; nt += 2) {
        const int u = nt * 16 + l16;
        const int slot = (quad + (u >> 2)) & 3;
        const bf16x8 bfrag = *(const bf16x8*)(smem + KOFF + u * 64 + slot * 16);
        f32x4 c = {0.f, 0.f, 0.f, 0.f};
        c = __builtin_amdgcn_mfma_f32_16x16x32_bf16(afrag, bfrag, c, 0, 0, 0);
#pragma unroll
        for (int r2 = 0; r2 < 4; ++r2) {
          const int qrow = mtile * 16 + quad * 4 + r2;
          ph[qrow * NCOLS + u] = f2h(c[r2]);
        }
      }
    }
    __syncthreads();   // (2) P raw ready; K region free

    // ---- issue next pass's K + V (drain hides under softmax + AV) ----
    if (pass < 2) {
      const unsigned tb_k = (unsigned)(b * Tv + st + pass + 1) * (Hv * Wv * 4);
      for (int s = 0; s < nk; ++s)
        gload_lds16(kin_h + tb_k + ksp[s], smem + KOFF + kch[s] * 1024 + lane * 16);
      const ushort* vpl =
          vin + (size_t)(head * 16 + b * Tv + st + pass + 1) * 32 * 4096;
      const unsigned vtn = ((pass + 1) & 1) ? VT1 : VT0;
#pragma unroll
      for (int it = 0; it < 2; ++it)
        gload_lds16(vpl + vofs[it], smem + vtn + (tid + it * 512) * 16);
    }

    // ---- softmax: 49 valid / query (7 runs of 7). 8 threads/row.
    // read+exp -> zero -> scatter; row touched only by its own 8-lane group
    // (same wave) -> wave-ordered, no intra barriers. ----
    {
      const ushort* Ps = (const ushort*)(smem + POFF) + qs * NCOLS;
      const float* rpb_l = (const float*)(smem + RPBOFF) + (rt_b + pass) * 169;
      float ex[7];
      int uu[7];
#pragma unroll
      for (int k = 0; k < 7; ++k) {
        const int e = l8s + 8 * k;
        const int a = (e * 37) >> 8;             // e/7 for e<64
        const int bb = e - 7 * a;
        uu[k] = (dh_s + a) * 16 + dw_s + bb;
        if (e < 49) {
          const float s = h2f(Ps[uu[k]]) + rpb_l[(rh0 + a) * 13 + rw0 + bb];
          ex[k] = __expf(s);
          sum += ex[k];
        }
      }
      if (pass == 2) {
        float sm = sum;
        sm += __shfl_xor(sm, 1);
        sm += __shfl_xor(sm, 2);
        sm += __shfl_xor(sm, 4);
        if (l8s == 0) ((float*)(smem + INVOFF))[qs] = 1.0f / sm;
      }
      __builtin_amdgcn_sched_barrier(0);         // reads before zeros
      {
        uint4* Pv = (uint4*)(smem + POFF + (size_t)qs * SVT);
#pragma unroll
        for (int c = 0; c < 4; ++c) {
          const int idx = l8s + 8 * c;
          if (idx < 29) Pv[idx] = make_uint4(0u, 0u, 0u, 0u);
        }
      }
      __builtin_amdgcn_sched_barrier(0);         // zeros before scatter
      ushort* Pr = (ushort*)(smem + POFF) + qs * NCOLS;
#pragma unroll
      for (int k = 0; k < 7; ++k) {
        const int e = l8s + 8 * k;
        if (e < 49) Pr[uu[k]] = f2bf16(ex[k]);
      }
    }
    __syncthreads();   // (3) P final

    // ---- AV: each wave all 7 kt from Vt[pass&1], accumulate ----
    {
      const unsigned vt = (pass & 1) ? VT1 : VT0;
      const unsigned char* Abase = smem + POFF + (size_t)(mtA * 16 + l16) * SVT;
#pragma unroll
      for (int kt = 0; kt < 7; ++kt) {
        const bf16x8 a  = *(const bf16x8*)(Abase + kt * 64 + quad * 16);
        const bf16x8 bb = *(const bf16x8*)(smem + vt +
                            ((vbase + kt * 64 + quad * 16) ^ vsw));
        o = __builtin_amdgcn_mfma_f32_16x16x32_bf16(a, bb, o, 0, 0, 0);
      }
    }
  }

  // ---- epilogue: normalize + store (R8-proven pattern, ideal write volume)
  {
    float* oout_h = oout + (size_t)head * MPOS * 32;
    const float* invArr = (const float*)(smem + INVOFF);
#pragma unroll
    for (int r2 = 0; r2 < 4; ++r2) {
      const int qrow = mtA * 16 + quad * 4 + r2;
      const float val = o[r2] * invArr[qrow];
      const int qh2 = h0 + (qrow >> 3), qw2 = w0 + (qrow & 7);
      const size_t qp2 = ((size_t)(b * Tv + t) * Hv + qh2) * Wv + qw2;
      oout_h[qp2 * 32 + dcol] = val;
    }
  }
}

// ---------------------------------------------------------------------------
extern "C" void kernel_launch(void* const* d_in, const int* in_sizes, int n_in,
                              void* d_out, int out_size, void* d_ws, size_t ws_size,
                              hipStream_t stream) {
  const float* x      = (const float*)d_in[0];
  const float* y      = (const float*)d_in[1];
  const float* qv_w   = (const float*)d_in[2];
  const float* qv_b   = (const float*)d_in[3];
  const float* k_w    = (const float*)d_in[4];
  const float* k_b    = (const float*)d_in[5];
  const float* proj_w = (const float*)d_in[6];
  const float* proj_b = (const float*)d_in[7];
  const float* rpb    = (const float*)d_in[8];
  float* out = (float*)d_out;

  const size_t elems = (size_t)MPOS * 128;        // 8,388,608
  ushort* qbuf = (ushort*)d_ws;                   // 16.8 MB (bf16, head-major)
  ushort* kbuf = qbuf + elems;                    // 16.8 MB (head-major)
  ushort* vbuf = kbuf + elems;                    // 16.8 MB (TRANSPOSED planes)
  float*  obuf = (float*)(vbuf + elems);          // 33.5 MB (head-major)
  ushort* wqvT   = (ushort*)(obuf + elems);
  ushort* wkT    = wqvT + 256 * KPAD;
  ushort* wpT_hi = wkT + 128 * KPAD;
  ushort* wpT_lo = wpT_hi + 128 * KPAD;

  preconvert    <<<256,  256, 0, stream>>>(qv_w, k_w, proj_w, wqvT, wkT, wpT_hi, wpT_lo);
  gemm_qvk      <<<1536, 512, 0, stream>>>(x, y, wqvT, wkT, qv_b, k_b, qbuf, vbuf, kbuf);
  na3d_tile     <<<4096, 512, 0, stream>>>(qbuf, kbuf, vbuf, rpb, obuf);
  gemm_proj_mfma<<<512,  512, 0, stream>>>(obuf, wpT_hi, wpT_lo, proj_b, out);
}